// Round 17
// baseline (34.431 us; speedup 1.0000x reference)
//
#include <hip/hip_runtime.h>

// SphericalVectorPool on MI355X — 1 wave = 1 anchor, 64-thread blocks.
// mu_j = 4/j => E_{j/2} = E_j^2 exactly: 8 v_exp_f32 + 8 v_mul per source.
// Each wave owns one anchor and all 2048 sources (16 iters x 2 sources/lane),
// f16 dot2 accumulation (v_dot2_f32_f16 into f32 v[64]). No LDS, no barriers:
// 4096 fully independent waves -> up to 16 blocks/CU of decoupled work to
// fill the issue bubbles left by exp->cvt->dot2 dep chains.
// Epilogue: bit-compaction transpose-reduce (63 shfl) -> lane j holds output
// j -> direct coalesced 256B store.

constexpr int NR    = 16;
constexpr int BATCH = 2;
constexpr int NSRC  = 2048;
constexpr int MOUT  = 2048;

typedef __fp16 h2 __attribute__((ext_vector_type(2)));

__global__ __launch_bounds__(256) void pack_kernel(
    const float* __restrict__ f,
    const float* __restrict__ coords,
    float4* __restrict__ packed)   // [B*N] of {x,y,z,f}
{
    int i = blockIdx.x * 256 + threadIdx.x;
    if (i < BATCH * NSRC) {
        packed[i] = make_float4(coords[i * 3 + 0], coords[i * 3 + 1],
                                coords[i * 3 + 2], f[i]);
    }
}

#define STAGE(P, CNT)                                                     \
    {                                                                     \
        const bool mybit = (lane >> (P)) & 1;                             \
        _Pragma("unroll")                                                 \
        for (int t = 0; t < ((CNT) / 2); ++t) {                           \
            const float lo = v[2 * t], hi = v[2 * t + 1];                 \
            const float send = mybit ? lo : hi;                           \
            const float keep = mybit ? hi : lo;                           \
            v[t] = keep + __shfl_xor(send, 1 << (P), 64);                 \
        }                                                                 \
    }

// sqrt-chain: 8 exp heads + 8 squares -> all 16 E values
__device__ inline void exp_chain(float dd, const float* __restrict__ mu,
                                 float* __restrict__ e) {
    e[15] = __builtin_amdgcn_exp2f(dd * mu[15]);  // E16
    e[14] = __builtin_amdgcn_exp2f(dd * mu[14]);  // E15
    e[13] = __builtin_amdgcn_exp2f(dd * mu[13]);  // E14
    e[12] = __builtin_amdgcn_exp2f(dd * mu[12]);  // E13
    e[11] = __builtin_amdgcn_exp2f(dd * mu[11]);  // E12
    e[10] = __builtin_amdgcn_exp2f(dd * mu[10]);  // E11
    e[9]  = __builtin_amdgcn_exp2f(dd * mu[9]);   // E10
    e[8]  = __builtin_amdgcn_exp2f(dd * mu[8]);   // E9
    e[7] = e[15] * e[15];   // E8  = E16^2
    e[6] = e[13] * e[13];   // E7  = E14^2
    e[5] = e[11] * e[11];   // E6  = E12^2
    e[4] = e[9]  * e[9];    // E5  = E10^2
    e[3] = e[7]  * e[7];    // E4  = E8^2
    e[2] = e[5]  * e[5];    // E3  = E6^2
    e[1] = e[3]  * e[3];    // E2  = E4^2
    e[0] = e[1]  * e[1];    // E1  = E2^2
}

__global__ __launch_bounds__(64, 1) void svp_kernel(
    const float4* __restrict__ packed, // [B,N] {x,y,z,f}
    const float* __restrict__ outc,    // [B,M,3]
    const float* __restrict__ mu,      // [16]
    const float* __restrict__ rn,      // [16]
    const float* __restrict__ an0,     // [1]
    const float* __restrict__ an1,     // [1]
    float* __restrict__ out)           // [B,M,64]
{
    const int lane = threadIdx.x;             // 0..63, one wave per block
    const int anchor = blockIdx.x;            // 0..4095
    const int b = anchor >> 11;

    const float NL2E = -1.44269504088896340736f;

    const float Rx = outc[(size_t)anchor * 3 + 0];
    const float Ry = outc[(size_t)anchor * 3 + 1];
    const float Rz = outc[(size_t)anchor * 3 + 2];

    float v[64];
#pragma unroll
    for (int j = 0; j < 64; ++j) v[j] = 0.f;

    const float4* pb = packed + (size_t)b * NSRC;

    for (int i = 0; i < NSRC / 128; ++i) {    // 16 iterations, 2 src/lane
        const float4 pA = pb[i * 128 + lane];
        const float4 pB = pb[i * 128 + 64 + lane];

        const float dxA = pA.x - Rx, dyA = pA.y - Ry, dzA = pA.z - Rz;
        const float dxB = pB.x - Rx, dyB = pB.y - Ry, dzB = pB.z - Rz;
        const float fvA = pA.w, fvB = pB.w;
        const float sqA = dxA * dxA + dyA * dyA + dzA * dzA;
        const float sqB = dxB * dxB + dyB * dyB + dzB * dzB;
        const float riA = __builtin_amdgcn_rsqf(sqA);
        const float riB = __builtin_amdgcn_rsqf(sqB);
        const float ddA = (sqA * riA) * NL2E;   // -log2e * |r-R|
        const float ddB = (sqB * riB) * NL2E;
        const float tA  = fvA * riA, tB = fvB * riB;
        const float fxA = tA * dxA, fyA = tA * dyA, fzA = tA * dzA;
        const float fxB = tB * dxB, fyB = tB * dyB, fzB = tB * dzB;

        float eA[NR], eB[NR];
        exp_chain(ddA, mu, eA);
        exp_chain(ddB, mu, eB);

        const h2 wv = __builtin_amdgcn_cvt_pkrtz(fvA, fvB);
        const h2 wx = __builtin_amdgcn_cvt_pkrtz(fxA, fxB);
        const h2 wy = __builtin_amdgcn_cvt_pkrtz(fyA, fyB);
        const h2 wz = __builtin_amdgcn_cvt_pkrtz(fzA, fzB);

#pragma unroll
        for (int k = 0; k < NR; ++k) {
            const h2 ek = __builtin_amdgcn_cvt_pkrtz(eA[k], eB[k]);
            v[k]      = __builtin_amdgcn_fdot2(ek, wv, v[k],      false);
            v[16 + k] = __builtin_amdgcn_fdot2(ek, wx, v[16 + k], false);
            v[32 + k] = __builtin_amdgcn_fdot2(ek, wy, v[32 + k], false);
            v[48 + k] = __builtin_amdgcn_fdot2(ek, wz, v[48 + k], false);
        }
    }

    STAGE(0, 64) STAGE(1, 32) STAGE(2, 16) STAGE(3, 8) STAGE(4, 4) STAGE(5, 2)
    // lane j now holds output j summed over all 64 lanes (= all 2048 sources)

    const float s = rn[lane & (NR - 1)] * (lane < NR ? an0[0] : an1[0]);
    out[(size_t)anchor * 64 + lane] = v[0] * s;
}

extern "C" void kernel_launch(void* const* d_in, const int* in_sizes, int n_in,
                              void* d_out, int out_size, void* d_ws, size_t ws_size,
                              hipStream_t stream) {
    const float* f      = (const float*)d_in[0];
    const float* coords = (const float*)d_in[1];
    const float* outc   = (const float*)d_in[2];
    const float* mu     = (const float*)d_in[3];
    const float* rn     = (const float*)d_in[4];
    const float* an0    = (const float*)d_in[5];
    const float* an1    = (const float*)d_in[6];
    float* out = (float*)d_out;
    float4* packed = (float4*)d_ws;   // B*N*16B = 64 KiB

    pack_kernel<<<(BATCH * NSRC + 255) / 256, 256, 0, stream>>>(f, coords, packed);

    const int anchors = BATCH * MOUT;              // 4096 waves, 1 per block
    svp_kernel<<<anchors, 64, 0, stream>>>(packed, outc, mu, rn, an0, an1, out);
}

// Round 18
// 29.550 us; speedup vs baseline: 1.1652x; 1.1652x over previous
//
#include <hip/hip_runtime.h>

// SphericalVectorPool on MI355X — single fused kernel (pack kernel removed).
// mu_j = 4/j => E_{j/2} = E_j^2 exactly: 8 v_exp_f32 + 8 v_mul per source.
// 1 wave = 1 anchor (4096 one-wave blocks, no LDS, no barriers). Each wave:
// 16 iters x 2 sources/lane, loading coords (3x dword) + f (dword) directly
// (R13 proved the in-loop load path is irrelevant: inputs are L2-resident).
// f16 dot2 accumulation into f32 v[64]. Epilogue: bit-compaction
// transpose-reduce (63 shfl) -> lane j holds output j -> 256B store.

constexpr int NR    = 16;
constexpr int BATCH = 2;
constexpr int NSRC  = 2048;
constexpr int MOUT  = 2048;

typedef __fp16 h2 __attribute__((ext_vector_type(2)));

#define STAGE(P, CNT)                                                     \
    {                                                                     \
        const bool mybit = (lane >> (P)) & 1;                             \
        _Pragma("unroll")                                                 \
        for (int t = 0; t < ((CNT) / 2); ++t) {                           \
            const float lo = v[2 * t], hi = v[2 * t + 1];                 \
            const float send = mybit ? lo : hi;                           \
            const float keep = mybit ? hi : lo;                           \
            v[t] = keep + __shfl_xor(send, 1 << (P), 64);                 \
        }                                                                 \
    }

// sqrt-chain: 8 exp heads + 8 squares -> all 16 E values
__device__ inline void exp_chain(float dd, const float* __restrict__ mu,
                                 float* __restrict__ e) {
    e[15] = __builtin_amdgcn_exp2f(dd * mu[15]);  // E16
    e[14] = __builtin_amdgcn_exp2f(dd * mu[14]);  // E15
    e[13] = __builtin_amdgcn_exp2f(dd * mu[13]);  // E14
    e[12] = __builtin_amdgcn_exp2f(dd * mu[12]);  // E13
    e[11] = __builtin_amdgcn_exp2f(dd * mu[11]);  // E12
    e[10] = __builtin_amdgcn_exp2f(dd * mu[10]);  // E11
    e[9]  = __builtin_amdgcn_exp2f(dd * mu[9]);   // E10
    e[8]  = __builtin_amdgcn_exp2f(dd * mu[8]);   // E9
    e[7] = e[15] * e[15];   // E8  = E16^2
    e[6] = e[13] * e[13];   // E7  = E14^2
    e[5] = e[11] * e[11];   // E6  = E12^2
    e[4] = e[9]  * e[9];    // E5  = E10^2
    e[3] = e[7]  * e[7];    // E4  = E8^2
    e[2] = e[5]  * e[5];    // E3  = E6^2
    e[1] = e[3]  * e[3];    // E2  = E4^2
    e[0] = e[1]  * e[1];    // E1  = E2^2
}

__global__ __launch_bounds__(64, 1) void svp_kernel(
    const float* __restrict__ f,       // [B,N]
    const float* __restrict__ coords,  // [B,N,3]
    const float* __restrict__ outc,    // [B,M,3]
    const float* __restrict__ mu,      // [16]
    const float* __restrict__ rn,      // [16]
    const float* __restrict__ an0,     // [1]
    const float* __restrict__ an1,     // [1]
    float* __restrict__ out)           // [B,M,64]
{
    const int lane = threadIdx.x;             // 0..63, one wave per block
    const int anchor = blockIdx.x;            // 0..4095
    const int b = anchor >> 11;

    const float NL2E = -1.44269504088896340736f;

    const float Rx = outc[(size_t)anchor * 3 + 0];
    const float Ry = outc[(size_t)anchor * 3 + 1];
    const float Rz = outc[(size_t)anchor * 3 + 2];

    float v[64];
#pragma unroll
    for (int j = 0; j < 64; ++j) v[j] = 0.f;

    const float* cb = coords + (size_t)b * NSRC * 3;
    const float* fb = f + (size_t)b * NSRC;

    for (int i = 0; i < NSRC / 128; ++i) {    // 16 iterations, 2 src/lane
        const int sA = i * 128 + lane;
        const int sB = sA + 64;
        const float cxA = cb[sA * 3 + 0], cyA = cb[sA * 3 + 1], czA = cb[sA * 3 + 2];
        const float cxB = cb[sB * 3 + 0], cyB = cb[sB * 3 + 1], czB = cb[sB * 3 + 2];
        const float fvA = fb[sA], fvB = fb[sB];

        const float dxA = cxA - Rx, dyA = cyA - Ry, dzA = czA - Rz;
        const float dxB = cxB - Rx, dyB = cyB - Ry, dzB = czB - Rz;
        const float sqA = dxA * dxA + dyA * dyA + dzA * dzA;
        const float sqB = dxB * dxB + dyB * dyB + dzB * dzB;
        const float riA = __builtin_amdgcn_rsqf(sqA);
        const float riB = __builtin_amdgcn_rsqf(sqB);
        const float ddA = (sqA * riA) * NL2E;   // -log2e * |r-R|
        const float ddB = (sqB * riB) * NL2E;
        const float tA  = fvA * riA, tB = fvB * riB;
        const float fxA = tA * dxA, fyA = tA * dyA, fzA = tA * dzA;
        const float fxB = tB * dxB, fyB = tB * dyB, fzB = tB * dzB;

        float eA[NR], eB[NR];
        exp_chain(ddA, mu, eA);
        exp_chain(ddB, mu, eB);

        const h2 wv = __builtin_amdgcn_cvt_pkrtz(fvA, fvB);
        const h2 wx = __builtin_amdgcn_cvt_pkrtz(fxA, fxB);
        const h2 wy = __builtin_amdgcn_cvt_pkrtz(fyA, fyB);
        const h2 wz = __builtin_amdgcn_cvt_pkrtz(fzA, fzB);

#pragma unroll
        for (int k = 0; k < NR; ++k) {
            const h2 ek = __builtin_amdgcn_cvt_pkrtz(eA[k], eB[k]);
            v[k]      = __builtin_amdgcn_fdot2(ek, wv, v[k],      false);
            v[16 + k] = __builtin_amdgcn_fdot2(ek, wx, v[16 + k], false);
            v[32 + k] = __builtin_amdgcn_fdot2(ek, wy, v[32 + k], false);
            v[48 + k] = __builtin_amdgcn_fdot2(ek, wz, v[48 + k], false);
        }
    }

    STAGE(0, 64) STAGE(1, 32) STAGE(2, 16) STAGE(3, 8) STAGE(4, 4) STAGE(5, 2)
    // lane j now holds output j summed over all 64 lanes (= all 2048 sources)

    const float s = rn[lane & (NR - 1)] * (lane < NR ? an0[0] : an1[0]);
    out[(size_t)anchor * 64 + lane] = v[0] * s;
}

extern "C" void kernel_launch(void* const* d_in, const int* in_sizes, int n_in,
                              void* d_out, int out_size, void* d_ws, size_t ws_size,
                              hipStream_t stream) {
    const float* f      = (const float*)d_in[0];
    const float* coords = (const float*)d_in[1];
    const float* outc   = (const float*)d_in[2];
    const float* mu     = (const float*)d_in[3];
    const float* rn     = (const float*)d_in[4];
    const float* an0    = (const float*)d_in[5];
    const float* an1    = (const float*)d_in[6];
    float* out = (float*)d_out;

    const int anchors = BATCH * MOUT;              // 4096 waves, 1 per block
    svp_kernel<<<anchors, 64, 0, stream>>>(f, coords, outc, mu, rn, an0, an1, out);
}